// Round 2
// baseline (186.581 us; speedup 1.0000x reference)
//
#include <hip/hip_runtime.h>

// ConvCapsMatrix EM routing, MI355X. Inputs FP32, output FP32.
// R19b: resubmit of R19 (infra failure, no data) with three fixes:
//  - __launch_bounds__(512,4) (NOT (512,8): forcing 8 waves/SIMD needs <=64
//    combined VGPRs vs ~100 live -> scratch spills in j-loop).
//  - caps_combine kernel: per-pos state (mu/isig/la/slog, 1088 f) computed
//    ONCE per iteration (576 blocks) instead of per stats-block (was
//    NCHUNK^2-quadratic partial re-reads + 3x transcendental recompute).
//    stats prologue = 34 coalesced global loads, no VALU, no extra barrier.
//    Also removes parity double-buffer: stats S->P, combine P->S.
//  - R18-style single-hop epilogue reduce part[8][544] (4 barriers, not 6);
//    LDS 21.7KB — residency is thread-capped at 4 blocks/CU, so LDS<=40KB free.
// Kept from R19: 6 chunks x 48 n -> grid 3456x512 (27648 waves, 3x R18 supply;
// wave supply is the measured lever: 4608->9216 moved VALUBusy 43->55%).
// Chunk-major bid: pos = bid % 576 (576%8==0) so a pos's 6 chunks and a
// chunk's consecutive blocks (same 98KB W panel) share an XCD L2.
// j-body numerics identical to R18 (exact ev/s division).

#define EPSV 1e-8f
#define NPOS 576
#define NCHUNK 6
#define CHN 48           // n's per chunk
#define PSZ 1056         // floats per partial chunk: 512 S1, 512 S2, 32 rs
#define SSZ 1088         // floats per pos state: 512 mu, 512 isig, 32 la, 32 slog

template <int CTRL>
__device__ __forceinline__ float dppf(float v) {
  return __int_as_float(__builtin_amdgcn_update_dpp(
      0, __float_as_int(v), CTRL, 0xf, 0xf, true));
}
__device__ __forceinline__ float swz16(float v) {   // lane ^ 16 within 32-groups
  return __int_as_float(__builtin_amdgcn_ds_swizzle(__float_as_int(v), 0x401F));
}
__device__ __forceinline__ float red_max32(float v) {
  v = fmaxf(v, dppf<0xB1>(v));
  v = fmaxf(v, dppf<0x4E>(v));
  v = fmaxf(v, dppf<0x141>(v));
  v = fmaxf(v, dppf<0x140>(v));
  v = fmaxf(v, swz16(v));
  return v;
}
__device__ __forceinline__ float red_sum32(float v) {
  v += dppf<0xB1>(v);
  v += dppf<0x4E>(v);
  v += dppf<0x141>(v);
  v += dppf<0x140>(v);
  v += swz16(v);
  return v;
}

__device__ __forceinline__ void compute_votes(const float* __restrict__ Wt,
                                              const float* __restrict__ xr,
                                              int n, int o, float* __restrict__ V)
{
  // W[k,l,c,o,y,z] flat = (n*32+o)*16 + y*4+z ; xr = local pose row (16 f)
  float Wf[16];
  {
    const float* wp = Wt + (((n << 5) + o) << 4);
#pragma unroll
    for (int i = 0; i < 4; ++i) {
      const float4 q = *(const float4*)(wp + (i << 2));
      Wf[i*4+0]=q.x; Wf[i*4+1]=q.y; Wf[i*4+2]=q.z; Wf[i*4+3]=q.w;
    }
  }
  float xv[16];
#pragma unroll
  for (int i = 0; i < 4; ++i) {
    const float4 q = *(const float4*)(xr + (i << 2));
    xv[i*4+0]=q.x; xv[i*4+1]=q.y; xv[i*4+2]=q.z; xv[i*4+3]=q.w;
  }
#pragma unroll
  for (int xi = 0; xi < 4; ++xi)
#pragma unroll
    for (int z = 0; z < 4; ++z)
      V[xi*4+z] = fmaf(xv[xi*4+0], Wf[z],
                  fmaf(xv[xi*4+1], Wf[4+z],
                  fmaf(xv[xi*4+2], Wf[8+z],
                       xv[xi*4+3]* Wf[12+z])));
}

// ---- stats kernel: one block per (pos, chunk). Reads state S, writes partials P.
// partial chunk layout: [0..511] S1(p*32+o), [512..1023] S2, [1024..1055] rs(o)
__global__ __launch_bounds__(512, 4) void caps_stats(
    const float* __restrict__ X, const float* __restrict__ A,
    const float* __restrict__ Wt,
    const float* __restrict__ Sb, float* __restrict__ P, int it)
{
  __shared__ float xp_s[CHN*16];   // 48 pose rows            3072 B
  __shared__ float a_s[CHN];       // activations              192 B
  __shared__ float part[8*544];    // per-wave partials      17408 B
  __shared__ float prs[8*32];      // per-wave sum Ra         1024 B

  const int t    = threadIdx.x;
  const int o    = t & 31;
  const int ng   = t >> 5;        // 0..15
  const int wv   = t >> 6;        // 0..7
  const int lane = t & 63;

  const int bid   = blockIdx.x;
  const int chunk = bid / NPOS;           // chunk-major: XCD = bid%8 = pos%8
  const int pos   = bid - chunk * NPOS;
  const int b  = pos / 144;
  const int r_ = pos - b*144;
  const int h  = r_ / 12;
  const int w  = r_ - (r_/12)*12;
  const int nbase = chunk * CHN;

  // ---- stage this chunk's 48 pose rows + activations
  if (t < 192) {
    const int r  = t >> 2, q4 = t & 3;
    const int n  = nbase + r;
    const int kl = n >> 5, c = n & 31;
    const int hy = h + kl/3, wx = w + (kl - (kl/3)*3);
    const float4 v = *(const float4*)(X + ((((b*14+hy)*14+wx) << 9) + (c << 4) + (q4 << 2)));
    *(float4*)(xp_s + (r << 4) + (q4 << 2)) = v;
  }
  if (t < CHN) {
    const int n  = nbase + t;
    const int kl = n >> 5, c = n & 31;
    const int hy = h + kl/3, wx = w + (kl - (kl/3)*3);
    a_s[t] = A[((b*14+hy)*14+wx)*32 + c];
  }

  // ---- load per-pos routing state (precomputed by caps_combine)
  float mu_r[16], isig_r[16];
  float la_r = 0.f, slog_r = 0.f;
  if (it > 0) {
    const float* S = Sb + (size_t)pos * SSZ;
#pragma unroll
    for (int p = 0; p < 16; ++p) {
      mu_r[p]   = S[p*32 + o];
      isig_r[p] = S[512 + p*32 + o];
    }
    la_r   = S[1024 + o];
    slog_r = S[1056 + o];
  } else {
#pragma unroll
    for (int p = 0; p < 16; ++p) { mu_r[p] = 0.f; isig_r[p] = 0.f; }
  }
  __syncthreads();                        // staging visibility

  // ---- fused stats pass over this chunk's n's (j = 3)
  float S1[16], S2[16];
#pragma unroll
  for (int p = 0; p < 16; ++p) { S1[p] = 0.f; S2[p] = 0.f; }
  float rs = 0.f;

#pragma unroll 1
  for (int j = 0; j < 3; ++j) {
    const int nl = ng + (j << 4);           // local row 0..47
    const int n  = nbase + nl;              // global n for W
    float V[16];
    compute_votes(Wt, xp_s + (nl << 4), n, o, V);

    float ra;
    if (it == 0) {
      ra = a_s[nl] * (1.0f/32.0f);
    } else {
      float q0 = 0.f, q1 = 0.f, q2 = 0.f, q3 = 0.f;
#pragma unroll
      for (int p = 0; p < 4; ++p) {
        float d;
        d = V[p]    - mu_r[p];    q0 = fmaf(d*d, isig_r[p],    q0);
        d = V[p+4]  - mu_r[p+4];  q1 = fmaf(d*d, isig_r[p+4],  q1);
        d = V[p+8]  - mu_r[p+8];  q2 = fmaf(d*d, isig_r[p+8],  q2);
        d = V[p+12] - mu_r[p+12]; q3 = fmaf(d*d, isig_r[p+12], q3);
      }
      const float q = slog_r + ((q0 + q1) + (q2 + q3));
      const float z = la_r - 0.5f*q;
      const float m  = red_max32(z);
      const float ev = __expf(z - m);
      const float s  = red_sum32(ev);
      ra = (ev / s) * a_s[nl];
    }
    rs += ra;
#pragma unroll
    for (int p = 0; p < 16; ++p) {
      const float rv = ra * V[p];
      S1[p] += rv;
      S2[p] = fmaf(rv, V[p], S2[p]);
    }
  }

  // ---- pair-combine ng via lane^32
#pragma unroll
  for (int p = 0; p < 16; ++p) {
    S1[p] += __shfl_xor(S1[p], 32);
    S2[p] += __shfl_xor(S2[p], 32);
  }
  rs += __shfl_xor(rs, 32);

  float* dst = P + ((size_t)pos * NCHUNK + chunk) * PSZ;

  // ---- phase A: S1 partials -> global (single-hop 8-wave reduce)
  if (lane < 32) {
    float* p1 = part + wv*544 + o*17;
#pragma unroll
    for (int p = 0; p < 16; ++p) p1[p] = S1[p];
    prs[wv*32 + o] = rs;
  }
  __syncthreads();
  {
    const int pi = t >> 5, oo = t & 31;
    float s1 = 0.f;
#pragma unroll
    for (int g = 0; g < 8; ++g) s1 += part[g*544 + oo*17 + pi];
    dst[t] = s1;                            // S1 at [0..511]
    if (t < 32) {
      float r = 0.f;
#pragma unroll
      for (int g = 0; g < 8; ++g) r += prs[(g << 5) + t];
      dst[1024 + t] = r;                    // rs at [1024..1055]
    }
  }
  __syncthreads();

  // ---- phase B: S2 partials -> global
  if (lane < 32) {
    float* p2 = part + wv*544 + o*17;
#pragma unroll
    for (int p = 0; p < 16; ++p) p2[p] = S2[p];
  }
  __syncthreads();
  {
    const int pi = t >> 5, oo = t & 31;
    float s2 = 0.f;
#pragma unroll
    for (int g = 0; g < 8; ++g) s2 += part[g*544 + oo*17 + pi];
    dst[512 + t] = s2;                      // S2 at [512..1023]
  }
}

// ---- combine kernel: partials P -> per-pos state S (mu/isig/la/slog)
__global__ __launch_bounds__(512, 4) void caps_combine(
    const float* __restrict__ P, const float* __restrict__ Bu,
    const float* __restrict__ Ba, float* __restrict__ Sb)
{
  __shared__ float lsig_t[512], rs_s[32];

  const int t   = threadIdx.x;
  const int o   = t & 31;
  const int pos = blockIdx.x;
  float* S = Sb + (size_t)pos * SSZ;
  {
    const float* hp = P + (size_t)pos * (NCHUNK * PSZ);
    float s1 = 0.f, s2 = 0.f, rsum = 0.f;
#pragma unroll
    for (int cc = 0; cc < NCHUNK; ++cc) {
      const float* hc = hp + cc * PSZ;
      s1   += hc[t];
      s2   += hc[512 + t];
      rsum += hc[1024 + o];
    }
    rsum += EPSV;
    const float mu = s1 / rsum;
    float var = s2 / rsum - mu*mu;
    var = fmaxf(var, 0.f);
    const float sg = var + EPSV;
    S[t]        = mu;
    S[512 + t]  = 1.0f / sg;
    lsig_t[t]   = __logf(sg);
    if (t < 32) rs_s[t] = rsum;            // t<32 => pi==0, o==t
  }
  __syncthreads();
  if (t < 32) {
    float slog = 0.f;
#pragma unroll
    for (int p = 0; p < 16; ++p) slog += lsig_t[p*32 + t];
    const float cost = rs_s[t] * (16.0f*Bu[t] + 0.5f*slog);
    const float av = 1.0f / (1.0f + __expf(-(Ba[t] - cost)));   // LAM=1
    S[1024 + t] = __logf(av + EPSV);
    S[1056 + t] = slog;
  }
}

// ---- final kernel: mu/aout from last stats partials -> Out
__global__ __launch_bounds__(512, 4) void caps_final(
    const float* __restrict__ P, const float* __restrict__ Bu,
    const float* __restrict__ Ba, float* __restrict__ Out)
{
  __shared__ float mu_t[512], lsig_t[512], rs_s[32], aout_s[32];

  const int t   = threadIdx.x;
  const int pos = blockIdx.x;
  {
    const int oo = t & 31;
    const float* hp = P + (size_t)pos * (NCHUNK * PSZ);
    float s1 = 0.f, s2 = 0.f, rsum = 0.f;
#pragma unroll
    for (int cc = 0; cc < NCHUNK; ++cc) {
      const float* hc = hp + cc * PSZ;
      s1   += hc[t];
      s2   += hc[512 + t];
      rsum += hc[1024 + oo];
    }
    rsum += EPSV;
    const float mu = s1 / rsum;
    float var = s2 / rsum - mu*mu;
    var = fmaxf(var, 0.f);
    mu_t[t]   = mu;
    lsig_t[t] = __logf(var + EPSV);
    if (t < 32) rs_s[t] = rsum;
  }
  __syncthreads();
  if (t < 32) {
    float slog = 0.f;
#pragma unroll
    for (int p = 0; p < 16; ++p) slog += lsig_t[p*32 + t];
    const float cost = rs_s[t] * (16.0f*Bu[t] + 0.5f*slog);
    aout_s[t] = 1.0f / (1.0f + __expf(-(Ba[t] - cost)));
  }
  __syncthreads();
  {
    const int oo = t >> 4, pi = t & 15;
    Out[pos*512 + t] = mu_t[pi*32 + oo];
  }
  if (t < 32) Out[294912 + pos*32 + t] = aout_s[t];
}

extern "C" void kernel_launch(void* const* d_in, const int* in_sizes, int n_in,
                              void* d_out, int out_size, void* d_ws, size_t ws_size,
                              hipStream_t stream) {
  (void)in_sizes; (void)n_in; (void)ws_size; (void)out_size;
  const float* X  = (const float*)d_in[0];
  const float* A  = (const float*)d_in[1];
  const float* Wt = (const float*)d_in[2];
  const float* Bu = (const float*)d_in[3];
  const float* Ba = (const float*)d_in[4];
  float* Out = (float*)d_out;

  float* P  = (float*)d_ws;                      // 576*6*1056 floats (~14.6 MB)
  float* Sb = P + (size_t)NPOS * NCHUNK * PSZ;   // 576*1088 floats  (~2.5 MB)

  hipLaunchKernelGGL(caps_stats, dim3(NPOS*NCHUNK), dim3(512), 0, stream,
                     X, A, Wt, (const float*)nullptr, P, 0);
  hipLaunchKernelGGL(caps_combine, dim3(NPOS), dim3(512), 0, stream,
                     P, Bu, Ba, Sb);
  hipLaunchKernelGGL(caps_stats, dim3(NPOS*NCHUNK), dim3(512), 0, stream,
                     X, A, Wt, Sb, P, 1);
  hipLaunchKernelGGL(caps_combine, dim3(NPOS), dim3(512), 0, stream,
                     P, Bu, Ba, Sb);
  hipLaunchKernelGGL(caps_stats, dim3(NPOS*NCHUNK), dim3(512), 0, stream,
                     X, A, Wt, Sb, P, 2);
  hipLaunchKernelGGL(caps_final, dim3(NPOS), dim3(512), 0, stream,
                     P, Bu, Ba, Out);
}